// Round 1
// baseline (631.474 us; speedup 1.0000x reference)
//
#include <hip/hip_runtime.h>
#include <math.h>

#define N_NODES 50000
#define N_EDGES 800000
#define HDIM 128
#define KB 4
#define DD 64
#define KD 256   // K*D

// ------------------------------------------------------------------ utility
__global__ void zero_int(int* __restrict__ p, int n) {
    int i = blockIdx.x * blockDim.x + threadIdx.x;
    if (i < n) p[i] = 0;
}

__global__ void count_deg(const int* __restrict__ dst, int* __restrict__ cnt, int e) {
    int i = blockIdx.x * blockDim.x + threadIdx.x;
    if (i < e) atomicAdd(&cnt[dst[i]], 1);
}

__global__ void calc_dinv(const int* __restrict__ cnt, float* __restrict__ dinv, int n) {
    int i = blockIdx.x * blockDim.x + threadIdx.x;
    if (i < n) dinv[i] = rsqrtf((float)(cnt[i] + 1));   // +1 self loop, always > 0
}

// single-block exclusive scan over cnt[0..n) -> offsets, cursor; offsets[n]=total
__global__ __launch_bounds__(1024)
void scan_kernel(const int* __restrict__ cnt, int* __restrict__ offsets,
                 int* __restrict__ cursor, int n) {
    __shared__ int wsum[16];
    __shared__ int carry_s;
    int tid = threadIdx.x;
    int lane = tid & 63, wid = tid >> 6;
    if (tid == 0) carry_s = 0;
    __syncthreads();
    for (int base = 0; base < n; base += 1024) {
        int i = base + tid;
        int v = (i < n) ? cnt[i] : 0;
        int x = v;
        #pragma unroll
        for (int off = 1; off < 64; off <<= 1) {
            int t = __shfl_up(x, off, 64);
            if (lane >= off) x += t;
        }
        if (lane == 63) wsum[wid] = x;
        __syncthreads();
        if (wid == 0) {
            int w = (lane < 16) ? wsum[lane] : 0;
            #pragma unroll
            for (int off = 1; off < 16; off <<= 1) {
                int t = __shfl_up(w, off, 64);
                if (lane >= off) w += t;
            }
            if (lane < 16) wsum[lane] = w;   // inclusive scan of wave sums
        }
        __syncthreads();
        int waveoff = (wid > 0) ? wsum[wid - 1] : 0;
        int incl = x + waveoff;
        int carry = carry_s;
        int excl = carry + incl - v;
        if (i < n) { offsets[i] = excl; cursor[i] = excl; }
        __syncthreads();                        // everyone read carry_s
        if (tid == 1023) carry_s = carry + incl; // chunk total
        __syncthreads();
    }
    if (tid == 0) offsets[n] = carry_s;
}

__global__ void fill_csr(const int* __restrict__ src, const int* __restrict__ dst,
                         int* __restrict__ cursor, int* __restrict__ csr, int e) {
    int i = blockIdx.x * blockDim.x + threadIdx.x;
    if (i < e) {
        int d = dst[i];
        int pos = atomicAdd(&cursor[d], 1);
        csr[pos] = src[i];
    }
}

// ------------------------------------------------------------------ propagate
// out[dst] = dinv[dst] * ( sum_in dinv[src]*h[src]  +  dinv[dst]*h[dst] )
// mode 1: out = prelu(out + bias, *alpha)
__global__ void prop_kernel(const float* __restrict__ hin, float* __restrict__ hout,
                            const int* __restrict__ csr, const int* __restrict__ offsets,
                            const float* __restrict__ dinv,
                            const float* __restrict__ bias, const float* __restrict__ alpha,
                            int mode, int n) {
    int gw = (blockIdx.x * blockDim.x + threadIdx.x) >> 6;
    int lane = threadIdx.x & 63;
    int nw = (gridDim.x * blockDim.x) >> 6;
    const float2* h2 = (const float2*)hin;
    for (int node = gw; node < n; node += nw) {
        int beg = offsets[node], end = offsets[node + 1];
        float ax = 0.f, ay = 0.f;
        for (int i = beg; i < end; ++i) {
            int s = csr[i];
            float w = dinv[s];
            float2 v = h2[(size_t)s * 64 + lane];
            ax = fmaf(w, v.x, ax);
            ay = fmaf(w, v.y, ay);
        }
        float dn = dinv[node];
        float2 sv = h2[(size_t)node * 64 + lane];
        ax = fmaf(dn, sv.x, ax);
        ay = fmaf(dn, sv.y, ay);
        ax *= dn; ay *= dn;
        if (mode) {
            float a = alpha[0];
            ax += bias[2 * lane]; ay += bias[2 * lane + 1];
            ax = ax >= 0.f ? ax : a * ax;
            ay = ay >= 0.f ? ay : a * ay;
        }
        float2 o; o.x = ax; o.y = ay;
        ((float2*)hout)[(size_t)node * 64 + lane] = o;
    }
}

// ------------------------------------------------------------------ GEMM
// mode 0: C0[row][ct*64+c] = sum_h A[row][h] * B0[h][ct*64+c]        (ldb=128)
// mode 1: ct<4: mu branch k=ct, else lv branch k=ct-4 (ldb=64)
//         mu = prelu(acc + bmu, amu) -> Cmu ; lv = sigmoid(prelu(acc+blv, alv)) -> Clv
__global__ __launch_bounds__(256)
void gemm_kernel(const float* __restrict__ A, int nrows,
                 const float* __restrict__ B0,
                 const float* __restrict__ Wmu, const float* __restrict__ Wlv,
                 const float* __restrict__ bmu, const float* __restrict__ blv,
                 const float* __restrict__ amu, const float* __restrict__ alv,
                 float* __restrict__ C0,
                 float* __restrict__ Cmu, float* __restrict__ Clv,
                 int mode) {
    __shared__ float As[128][64];   // [h][r]  (transposed A tile)
    __shared__ float Bs[128][64];   // [h][c]
    int ct = blockIdx.x, mt = blockIdx.y;
    int row0 = mt * 64;
    int tid = threadIdx.x;

    // stage A tile transposed: 64 rows x 128 h
    #pragma unroll
    for (int it = 0; it < 8; ++it) {
        int idx = tid + it * 256;
        int r = idx & 63;
        int h4 = (idx >> 6) << 2;
        int row = row0 + r;
        float4 v = make_float4(0.f, 0.f, 0.f, 0.f);
        if (row < nrows) v = *(const float4*)(A + (size_t)row * HDIM + h4);
        As[h4 + 0][r] = v.x; As[h4 + 1][r] = v.y;
        As[h4 + 2][r] = v.z; As[h4 + 3][r] = v.w;
    }
    // stage B tile
    const float* Bsrc;
    int ldb;
    if (mode == 0) { Bsrc = B0 + ct * 64; ldb = HDIM; }
    else {
        Bsrc = (ct < 4) ? (Wmu + (size_t)ct * HDIM * DD)
                        : (Wlv + (size_t)(ct - 4) * HDIM * DD);
        ldb = DD;
    }
    #pragma unroll
    for (int it = 0; it < 8; ++it) {
        int idx = tid + it * 256;
        int h = idx >> 4;
        int c4 = (idx & 15) << 2;
        float4 v = *(const float4*)(Bsrc + (size_t)h * ldb + c4);
        *(float4*)(&Bs[h][c4]) = v;
    }
    __syncthreads();

    int tx = tid & 15, ty = tid >> 4;
    float acc[4][4] = {};
    #pragma unroll 4
    for (int h = 0; h < 128; ++h) {
        float4 av = *(const float4*)(&As[h][ty * 4]);
        float4 bv = *(const float4*)(&Bs[h][tx * 4]);
        float ar[4] = {av.x, av.y, av.z, av.w};
        float brr[4] = {bv.x, bv.y, bv.z, bv.w};
        #pragma unroll
        for (int i = 0; i < 4; ++i)
            #pragma unroll
            for (int j = 0; j < 4; ++j)
                acc[i][j] = fmaf(ar[i], brr[j], acc[i][j]);
    }

    if (mode == 0) {
        #pragma unroll
        for (int i = 0; i < 4; ++i) {
            int row = row0 + ty * 4 + i;
            if (row < nrows) {
                float4 v = make_float4(acc[i][0], acc[i][1], acc[i][2], acc[i][3]);
                *(float4*)(C0 + (size_t)row * HDIM + ct * 64 + tx * 4) = v;
            }
        }
    } else {
        int k = ct & 3;
        bool is_mu = ct < 4;
        const float* bp = (is_mu ? bmu : blv) + k * DD;
        float a = (is_mu ? amu : alv)[k];
        float4 bb = *(const float4*)(bp + tx * 4);
        float bbr[4] = {bb.x, bb.y, bb.z, bb.w};
        float* outp = is_mu ? Cmu : Clv;
        #pragma unroll
        for (int i = 0; i < 4; ++i) {
            int row = row0 + ty * 4 + i;
            if (row < nrows) {
                float v[4];
                #pragma unroll
                for (int j = 0; j < 4; ++j) {
                    float t = acc[i][j] + bbr[j];
                    t = t >= 0.f ? t : a * t;
                    if (!is_mu) t = 1.f / (1.f + __expf(-t));
                    v[j] = t;
                }
                *(float4*)(outp + (size_t)row * KD + k * DD + tx * 4) =
                    make_float4(v[0], v[1], v[2], v[3]);
            }
        }
    }
}

// ------------------------------------------------------------------ reparam + r
__global__ void hk_kernel(const float* __restrict__ mu, const float* __restrict__ lv,
                          const float* __restrict__ eps, const float* __restrict__ Wr,
                          const float* __restrict__ br, float* __restrict__ hk,
                          float* __restrict__ r, int n) {
    int gw = (blockIdx.x * blockDim.x + threadIdx.x) >> 6;
    int lane = threadIdx.x & 63;
    if (gw >= n) return;
    size_t base = (size_t)gw * KD;
    #pragma unroll
    for (int k = 0; k < 4; ++k) {
        int c = k * 64 + lane;
        float m = mu[base + c], v = lv[base + c], e = eps[base + c];
        float h = fmaf(e, __expf(0.5f * v), m);
        hk[base + c] = h;
        float t = h * Wr[k * 64 + lane];
        #pragma unroll
        for (int off = 32; off >= 1; off >>= 1) t += __shfl_xor(t, off, 64);
        if (lane == 0) r[(size_t)gw * 4 + k] = 1.f / (1.f + __expf(-(t + br[k])));
    }
}

// ------------------------------------------------------------------ launch
extern "C" void kernel_launch(void* const* d_in, const int* in_sizes, int n_in,
                              void* d_out, int out_size, void* d_ws, size_t ws_size,
                              hipStream_t stream) {
    const float* x   = (const float*)d_in[0];
    const int*   ei  = (const int*)d_in[1];
    const float* W1  = (const float*)d_in[2];
    const float* b1  = (const float*)d_in[3];
    const float* a1  = (const float*)d_in[4];
    const float* W2  = (const float*)d_in[5];
    const float* b2  = (const float*)d_in[6];
    const float* a2  = (const float*)d_in[7];
    const float* Wmu = (const float*)d_in[8];
    const float* bmu = (const float*)d_in[9];
    const float* amu = (const float*)d_in[10];
    const float* Wlv = (const float*)d_in[11];
    const float* blv = (const float*)d_in[12];
    const float* alv = (const float*)d_in[13];
    const float* Wr  = (const float*)d_in[14];
    const float* br  = (const float*)d_in[15];
    const float* eps = (const float*)d_in[16];

    float* out      = (float*)d_out;
    float* out_hgcn = out;                                  // N*128
    float* out_lv   = out + (size_t)N_NODES * HDIM;         // N*256
    float* out_mu   = out_lv + (size_t)N_NODES * KD;        // N*256
    float* out_hk   = out_mu + (size_t)N_NODES * KD;        // N*256
    float* out_r    = out_hk + (size_t)N_NODES * KD;        // N*4

    char* ws = (char*)d_ws;
    int*   cnt     = (int*)ws;                      // N ints
    int*   offsets = (int*)(ws + 204800);           // N+1 ints
    int*   cursor  = (int*)(ws + 409600);           // N ints
    int*   csr     = (int*)(ws + 614400);           // E ints
    float* dinv    = (float*)(ws + 3814400);        // N floats

    // ping-pong N*128 buffers live in the hk output region (fully rewritten at the end)
    float* bufA = out_hk;                            // N*128
    float* bufB = out_hk + (size_t)N_NODES * HDIM;   // N*128

    const int* e_src = ei;
    const int* e_dst = ei + N_EDGES;

    zero_int <<<(N_NODES + 255) / 256, 256, 0, stream>>>(cnt, N_NODES);
    count_deg<<<(N_EDGES + 255) / 256, 256, 0, stream>>>(e_dst, cnt, N_EDGES);
    calc_dinv<<<(N_NODES + 255) / 256, 256, 0, stream>>>(cnt, dinv, N_NODES);
    scan_kernel<<<1, 1024, 0, stream>>>(cnt, offsets, cursor, N_NODES);
    fill_csr <<<(N_EDGES + 255) / 256, 256, 0, stream>>>(e_src, e_dst, cursor, csr, N_EDGES);

    dim3 g2(2, 782), g8(8, 782);
    // bufA = x @ W1
    gemm_kernel<<<g2, 256, 0, stream>>>(x, N_NODES, W1,
        nullptr, nullptr, nullptr, nullptr, nullptr, nullptr, bufA, nullptr, nullptr, 0);
    // bufB = h = prelu(prop(bufA) + b1, a1)
    prop_kernel<<<12500, 256, 0, stream>>>(bufA, bufB, csr, offsets, dinv, b1, a1, 1, N_NODES);
    // bufA = h @ W2
    gemm_kernel<<<g2, 256, 0, stream>>>(bufB, N_NODES, W2,
        nullptr, nullptr, nullptr, nullptr, nullptr, nullptr, bufA, nullptr, nullptr, 0);
    // hgcn = prelu(prop(bufA) + b2, a2)   -> output 0
    prop_kernel<<<12500, 256, 0, stream>>>(bufA, out_hgcn, csr, offsets, dinv, b2, a2, 1, N_NODES);
    // bufB = p = prop(hgcn)
    prop_kernel<<<12500, 256, 0, stream>>>(out_hgcn, bufB, csr, offsets, dinv, nullptr, nullptr, 0, N_NODES);
    // mu / logvar outputs (fused bias+prelu+sigmoid)
    gemm_kernel<<<g8, 256, 0, stream>>>(bufB, N_NODES, nullptr,
        Wmu, Wlv, bmu, blv, amu, alv, nullptr, out_mu, out_lv, 1);
    // hk + r  (overwrites the scratch region with the real hk output)
    hk_kernel<<<12500, 256, 0, stream>>>(out_mu, out_lv, eps, Wr, br, out_hk, out_r, N_NODES);
}

// Round 2
// 357.514 us; speedup vs baseline: 1.7663x; 1.7663x over previous
//
#include <hip/hip_runtime.h>
#include <math.h>

#define N_NODES 50000
#define N_EDGES 800000
#define HDIM 128
#define KD 256   // K*D

typedef float f32x4 __attribute__((ext_vector_type(4)));
typedef short s16x8 __attribute__((ext_vector_type(8)));

__device__ __forceinline__ ushort f2b(float f) {
    union { float f; unsigned u; } x; x.f = f;
    unsigned u = x.u;
    return (ushort)((u + 0x7FFF + ((u >> 16) & 1)) >> 16);   // RNE
}
__device__ __forceinline__ float b2f(ushort h) {
    union { unsigned u; float f; } x; x.u = ((unsigned)h) << 16; return x.f;
}

// ------------------------------------------------------------------ CSR build
__global__ void zero_int(int* __restrict__ p, int n) {
    int i = blockIdx.x * blockDim.x + threadIdx.x;
    if (i < n) p[i] = 0;
}

__global__ void count_deg(const int* __restrict__ dst, int* __restrict__ cnt, int e) {
    int i = blockIdx.x * blockDim.x + threadIdx.x;
    if (i < e) atomicAdd(&cnt[dst[i]], 1);
}

__global__ void calc_dinv(const int* __restrict__ cnt, float* __restrict__ dinv, int n) {
    int i = blockIdx.x * blockDim.x + threadIdx.x;
    if (i < n) dinv[i] = rsqrtf((float)(cnt[i] + 1));
}

__global__ __launch_bounds__(1024)
void scan_kernel(const int* __restrict__ cnt, int* __restrict__ offsets,
                 int* __restrict__ cursor, int n) {
    __shared__ int wsum[16];
    __shared__ int carry_s;
    int tid = threadIdx.x;
    int lane = tid & 63, wid = tid >> 6;
    if (tid == 0) carry_s = 0;
    __syncthreads();
    for (int base = 0; base < n; base += 1024) {
        int i = base + tid;
        int v = (i < n) ? cnt[i] : 0;
        int x = v;
        #pragma unroll
        for (int off = 1; off < 64; off <<= 1) {
            int t = __shfl_up(x, off, 64);
            if (lane >= off) x += t;
        }
        if (lane == 63) wsum[wid] = x;
        __syncthreads();
        if (wid == 0) {
            int w = (lane < 16) ? wsum[lane] : 0;
            #pragma unroll
            for (int off = 1; off < 16; off <<= 1) {
                int t = __shfl_up(w, off, 64);
                if (lane >= off) w += t;
            }
            if (lane < 16) wsum[lane] = w;
        }
        __syncthreads();
        int waveoff = (wid > 0) ? wsum[wid - 1] : 0;
        int incl = x + waveoff;
        int carry = carry_s;
        int excl = carry + incl - v;
        if (i < n) { offsets[i] = excl; cursor[i] = excl; }
        __syncthreads();
        if (tid == 1023) carry_s = carry + incl;
        __syncthreads();
    }
    if (tid == 0) offsets[n] = carry_s;
}

__global__ void fill_csr(const int* __restrict__ src, const int* __restrict__ dst,
                         int* __restrict__ cursor, int* __restrict__ csr, int e) {
    int i = blockIdx.x * blockDim.x + threadIdx.x;
    if (i < e) {
        int d = dst[i];
        int pos = atomicAdd(&cursor[d], 1);
        csr[pos] = src[i];
    }
}

// ------------------------------------------------------------------ prep
// x (fp32) -> bf16, pre-scaled by dinv[row]
__global__ void conv_x(const float4* __restrict__ x, ushort4* __restrict__ o,
                       const float* __restrict__ dinv, int n4) {
    int i = blockIdx.x * 256 + threadIdx.x;
    if (i >= n4) return;
    int row = i >> 5;                 // 32 float4 per row
    float dv = dinv[row];
    float4 v = x[i];
    ushort4 u;
    u.x = f2b(v.x * dv); u.y = f2b(v.y * dv);
    u.z = f2b(v.z * dv); u.w = f2b(v.w * dv);
    o[i] = u;
}

// transpose + bf16 all weights: W1T[n][k], W2T[n][k], Bt3[k][n(mu|lv)][h]
__global__ void prep_w(const float* __restrict__ W1, const float* __restrict__ W2,
                       const float* __restrict__ Wmu, const float* __restrict__ Wlv,
                       ushort* __restrict__ w1t, ushort* __restrict__ w2t,
                       ushort* __restrict__ bt3) {
    int i = blockIdx.x * 256 + threadIdx.x;
    if (i < 16384) {
        int nn = i >> 7, k = i & 127;
        w1t[i] = f2b(W1[k * 128 + nn]);
    } else if (i < 32768) {
        int j = i - 16384; int nn = j >> 7, k = j & 127;
        w2t[j] = f2b(W2[k * 128 + nn]);
    } else if (i < 98304) {
        int j = i - 32768;                 // ((k*128 + n)*128 + h)
        int h = j & 127; int nk = j >> 7; int nn = nk & 127; int k = nk >> 7;
        float v = (nn < 64) ? Wmu[k * 8192 + h * 64 + nn]
                            : Wlv[k * 8192 + h * 64 + (nn - 64)];
        bt3[j] = f2b(v);
    }
}

// ------------------------------------------------------------------ propagate (bf16)
// input rows are PRE-SCALED by dinv[src]; out[i] = dinv[i] * (sum_nbr in[s] + in[i])
__global__ __launch_bounds__(256)
void prop_b(const ushort2* __restrict__ hin, ushort2* __restrict__ hout,
            const int* __restrict__ csr, const int* __restrict__ offsets,
            const float* __restrict__ dinv, int n) {
    int gw = blockIdx.x * 4 + (threadIdx.x >> 6);
    int lane = threadIdx.x & 63;
    if (gw >= n) return;
    int beg = offsets[gw], end = offsets[gw + 1];
    float ax = 0.f, ay = 0.f;
    for (int i = beg; i < end; i += 64) {
        int cnt = end - i; if (cnt > 64) cnt = 64;
        int sidx = (lane < cnt) ? csr[i + lane] : 0;
        int j = 0;
        for (; j + 1 < cnt; j += 2) {
            int s0 = __shfl(sidx, j, 64);
            int s1 = __shfl(sidx, j + 1, 64);
            ushort2 v0 = hin[(size_t)s0 * 64 + lane];
            ushort2 v1 = hin[(size_t)s1 * 64 + lane];
            ax += b2f(v0.x) + b2f(v1.x);
            ay += b2f(v0.y) + b2f(v1.y);
        }
        if (j < cnt) {
            int s0 = __shfl(sidx, j, 64);
            ushort2 v0 = hin[(size_t)s0 * 64 + lane];
            ax += b2f(v0.x);
            ay += b2f(v0.y);
        }
    }
    ushort2 sv = hin[(size_t)gw * 64 + lane];
    ax += b2f(sv.x); ay += b2f(sv.y);
    float dn = dinv[gw];
    ax *= dn; ay *= dn;
    ushort2 o; o.x = f2b(ax); o.y = f2b(ay);
    hout[(size_t)gw * 64 + lane] = o;
}

// ------------------------------------------------------------------ MFMA GEMM (M x 128 @ 128 x 128)
// C = prelu(A@B + bias, alpha); Cb (bf16) = C * dinv[row] (feeds next prop)
// MODE 1 additionally writes fp32 C to Cf (hgcn output)
template<int MODE>
__global__ __launch_bounds__(256)
void gemm12(const ushort* __restrict__ A, const ushort* __restrict__ Bt,
            const float* __restrict__ bias, const float* __restrict__ alpha,
            const float* __restrict__ dinv,
            float* __restrict__ Cf, ushort* __restrict__ Cb, int nrows) {
    __shared__ char As[32768];
    __shared__ char Bs[32768];
    int tid = threadIdx.x;
    int row0 = blockIdx.x * 128;
    #pragma unroll
    for (int it = 0; it < 8; ++it) {
        int idx = tid + it * 256;
        int r = idx >> 4, cb = (idx & 15) << 4;
        int sw = cb ^ ((r & 15) << 4);
        uint4 v = make_uint4(0, 0, 0, 0);
        int row = row0 + r;
        if (row < nrows) v = *(const uint4*)((const char*)A + (size_t)row * 256 + cb);
        *(uint4*)(As + r * 256 + sw) = v;
        uint4 bv = *(const uint4*)((const char*)Bt + (size_t)idx * 16);
        *(uint4*)(Bs + r * 256 + sw) = bv;
    }
    __syncthreads();

    int w = tid >> 6, lane = tid & 63;
    int bq = lane >> 4, tr = lane & 15;
    f32x4 acc[2][8];
    #pragma unroll
    for (int mi = 0; mi < 2; ++mi)
        #pragma unroll
        for (int nj = 0; nj < 8; ++nj)
            acc[mi][nj] = (f32x4){0.f, 0.f, 0.f, 0.f};

    #pragma unroll
    for (int s = 0; s < 4; ++s) {
        int xoff = (s * 64 + bq * 16) ^ ((tr & 15) << 4);
        s16x8 af[2], bfr[8];
        #pragma unroll
        for (int mi = 0; mi < 2; ++mi)
            af[mi] = *(const s16x8*)(As + (w * 32 + mi * 16 + tr) * 256 + xoff);
        #pragma unroll
        for (int nj = 0; nj < 8; ++nj)
            bfr[nj] = *(const s16x8*)(Bs + (nj * 16 + tr) * 256 + xoff);
        #pragma unroll
        for (int mi = 0; mi < 2; ++mi)
            #pragma unroll
            for (int nj = 0; nj < 8; ++nj)
                acc[mi][nj] = __builtin_amdgcn_mfma_f32_16x16x32_bf16(af[mi], bfr[nj], acc[mi][nj], 0, 0, 0);
    }

    int g = lane >> 4, c = lane & 15;
    float aval = alpha[0];
    float bb[8];
    #pragma unroll
    for (int nj = 0; nj < 8; ++nj) bb[nj] = bias[nj * 16 + c];
    #pragma unroll
    for (int mi = 0; mi < 2; ++mi) {
        #pragma unroll
        for (int j = 0; j < 4; ++j) {
            int row = row0 + w * 32 + mi * 16 + g * 4 + j;
            if (row >= nrows) continue;
            float dv = dinv[row];
            #pragma unroll
            for (int nj = 0; nj < 8; ++nj) {
                int col = nj * 16 + c;
                float t = acc[mi][nj][j] + bb[nj];
                t = t >= 0.f ? t : aval * t;
                if (MODE) Cf[(size_t)row * 128 + col] = t;
                Cb[(size_t)row * 128 + col] = f2b(t * dv);
            }
        }
    }
}

// ------------------------------------------------------------------ mu/lv GEMM (+ fused hk, r)
// blockIdx.x = k; B tile = Bt3[k] : cols 0-63 mu, 64-127 lv
template<int FUSED>
__global__ __launch_bounds__(256)
void gemm3(const ushort* __restrict__ A, const ushort* __restrict__ Bt3,
           const float* __restrict__ bmu, const float* __restrict__ blv,
           const float* __restrict__ amu, const float* __restrict__ alv,
           const float* __restrict__ Wr, const float* __restrict__ br,
           const float* __restrict__ eps,
           float* __restrict__ out_mu, float* __restrict__ out_lv,
           float* __restrict__ out_hk, float* __restrict__ out_r, int nrows) {
    __shared__ char As[32768];
    __shared__ char Bs[32768];
    int tid = threadIdx.x;
    int k = blockIdx.x;
    int row0 = blockIdx.y * 128;
    const ushort* Bt = Bt3 + (size_t)k * 16384;
    #pragma unroll
    for (int it = 0; it < 8; ++it) {
        int idx = tid + it * 256;
        int r = idx >> 4, cb = (idx & 15) << 4;
        int sw = cb ^ ((r & 15) << 4);
        uint4 v = make_uint4(0, 0, 0, 0);
        int row = row0 + r;
        if (row < nrows) v = *(const uint4*)((const char*)A + (size_t)row * 256 + cb);
        *(uint4*)(As + r * 256 + sw) = v;
        uint4 bv = *(const uint4*)((const char*)Bt + (size_t)idx * 16);
        *(uint4*)(Bs + r * 256 + sw) = bv;
    }
    __syncthreads();

    int w = tid >> 6, lane = tid & 63;
    int bq = lane >> 4, tr = lane & 15;
    f32x4 acc[2][8];
    #pragma unroll
    for (int mi = 0; mi < 2; ++mi)
        #pragma unroll
        for (int nj = 0; nj < 8; ++nj)
            acc[mi][nj] = (f32x4){0.f, 0.f, 0.f, 0.f};

    #pragma unroll
    for (int s = 0; s < 4; ++s) {
        int xoff = (s * 64 + bq * 16) ^ ((tr & 15) << 4);
        s16x8 af[2], bfr[8];
        #pragma unroll
        for (int mi = 0; mi < 2; ++mi)
            af[mi] = *(const s16x8*)(As + (w * 32 + mi * 16 + tr) * 256 + xoff);
        #pragma unroll
        for (int nj = 0; nj < 8; ++nj)
            bfr[nj] = *(const s16x8*)(Bs + (nj * 16 + tr) * 256 + xoff);
        #pragma unroll
        for (int mi = 0; mi < 2; ++mi)
            #pragma unroll
            for (int nj = 0; nj < 8; ++nj)
                acc[mi][nj] = __builtin_amdgcn_mfma_f32_16x16x32_bf16(af[mi], bfr[nj], acc[mi][nj], 0, 0, 0);
    }

    int g = lane >> 4, c = lane & 15;
    float amuv = amu[k], alvv = alv[k];
    float brk = br[k];
    float bmv[4], blvb[4], wrv[4];
    #pragma unroll
    for (int nj = 0; nj < 4; ++nj) {
        int d = nj * 16 + c;
        bmv[nj] = bmu[k * 64 + d];
        blvb[nj] = blv[k * 64 + d];
        wrv[nj] = FUSED ? Wr[k * 64 + d] : 0.f;
    }
    #pragma unroll
    for (int mi = 0; mi < 2; ++mi) {
        float rsum[4] = {0.f, 0.f, 0.f, 0.f};
        #pragma unroll
        for (int j = 0; j < 4; ++j) {
            int row = row0 + w * 32 + mi * 16 + g * 4 + j;
            if (row >= nrows) continue;
            #pragma unroll
            for (int nj = 0; nj < 4; ++nj) {
                int d = nj * 16 + c;
                size_t oc = (size_t)row * KD + k * 64 + d;
                float m_ = acc[mi][nj][j] + bmv[nj];
                m_ = m_ >= 0.f ? m_ : amuv * m_;
                float l_ = acc[mi][nj + 4][j] + blvb[nj];
                l_ = l_ >= 0.f ? l_ : alvv * l_;
                l_ = 1.f / (1.f + __expf(-l_));
                out_mu[oc] = m_;
                out_lv[oc] = l_;
                if (FUSED) {
                    float h = fmaf(eps[oc], __expf(0.5f * l_), m_);
                    out_hk[oc] = h;
                    rsum[j] = fmaf(h, wrv[nj], rsum[j]);
                }
            }
        }
        if (FUSED) {
            #pragma unroll
            for (int j = 0; j < 4; ++j) {
                float t = rsum[j];
                t += __shfl_xor(t, 1, 64);
                t += __shfl_xor(t, 2, 64);
                t += __shfl_xor(t, 4, 64);
                t += __shfl_xor(t, 8, 64);
                if (c == 0) {
                    int row = row0 + w * 32 + mi * 16 + g * 4 + j;
                    if (row < nrows)
                        out_r[(size_t)row * 4 + k] = 1.f / (1.f + __expf(-(t + brk)));
                }
            }
        }
    }
}

// ------------------------------------------------------------------ fallback reparam + r
__global__ void hk_kernel(const float* __restrict__ mu, const float* __restrict__ lv,
                          const float* __restrict__ eps, const float* __restrict__ Wr,
                          const float* __restrict__ br, float* __restrict__ hk,
                          float* __restrict__ r, int n) {
    int gw = (blockIdx.x * blockDim.x + threadIdx.x) >> 6;
    int lane = threadIdx.x & 63;
    if (gw >= n) return;
    size_t base = (size_t)gw * KD;
    #pragma unroll
    for (int k = 0; k < 4; ++k) {
        int c = k * 64 + lane;
        float m = mu[base + c], v = lv[base + c], e = eps[base + c];
        float h = fmaf(e, __expf(0.5f * v), m);
        hk[base + c] = h;
        float t = h * Wr[k * 64 + lane];
        #pragma unroll
        for (int off = 32; off >= 1; off >>= 1) t += __shfl_xor(t, off, 64);
        if (lane == 0) r[(size_t)gw * 4 + k] = 1.f / (1.f + __expf(-(t + br[k])));
    }
}

// ------------------------------------------------------------------ launch
extern "C" void kernel_launch(void* const* d_in, const int* in_sizes, int n_in,
                              void* d_out, int out_size, void* d_ws, size_t ws_size,
                              hipStream_t stream) {
    const float* x   = (const float*)d_in[0];
    const int*   ei  = (const int*)d_in[1];
    const float* W1  = (const float*)d_in[2];
    const float* b1  = (const float*)d_in[3];
    const float* a1  = (const float*)d_in[4];
    const float* W2  = (const float*)d_in[5];
    const float* b2  = (const float*)d_in[6];
    const float* a2  = (const float*)d_in[7];
    const float* Wmu = (const float*)d_in[8];
    const float* bmu = (const float*)d_in[9];
    const float* amu = (const float*)d_in[10];
    const float* Wlv = (const float*)d_in[11];
    const float* blv = (const float*)d_in[12];
    const float* alv = (const float*)d_in[13];
    const float* Wr  = (const float*)d_in[14];
    const float* br  = (const float*)d_in[15];
    const float* eps = (const float*)d_in[16];

    float* out      = (float*)d_out;
    float* out_hgcn = out;                                  // N*128
    float* out_lv   = out + (size_t)N_NODES * HDIM;         // N*256
    float* out_mu   = out_lv + (size_t)N_NODES * KD;        // N*256
    float* out_hk   = out_mu + (size_t)N_NODES * KD;        // N*256
    float* out_r    = out_hk + (size_t)N_NODES * KD;        // N*4

    char* ws = (char*)d_ws;
    int*    cnt     = (int*)ws;                       // N ints
    int*    offsets = (int*)(ws + 204800);            // N+1 ints
    int*    cursor  = (int*)(ws + 409600);            // N ints
    int*    csr     = (int*)(ws + 614400);            // E ints
    float*  dinv    = (float*)(ws + 3814400);         // N floats
    ushort* w1t     = (ushort*)(ws + 4014592);        // 16384 bf16
    ushort* w2t     = (ushort*)(ws + 4047360);        // 16384 bf16
    ushort* bt3     = (ushort*)(ws + 4080128);        // 65536 bf16 (ends 4211200)

    // bf16 N x 128 slots inside the hk output region (fully rewritten at the end)
    ushort* S0 = (ushort*)out_hk;
    ushort* S1 = S0 + (size_t)N_NODES * HDIM;
    ushort* S2 = S1 + (size_t)N_NODES * HDIM;
    ushort* S3 = S2 + (size_t)N_NODES * HDIM;

    const size_t P_OFF = 4211264;
    const bool fused = ws_size >= P_OFF + (size_t)N_NODES * HDIM * 2;
    ushort* P = fused ? (ushort*)(ws + P_OFF) : S1;

    const int* e_src = ei;
    const int* e_dst = ei + N_EDGES;

    zero_int <<<(N_NODES + 255) / 256, 256, 0, stream>>>(cnt, N_NODES);
    count_deg<<<(N_EDGES + 255) / 256, 256, 0, stream>>>(e_dst, cnt, N_EDGES);
    calc_dinv<<<(N_NODES + 255) / 256, 256, 0, stream>>>(cnt, dinv, N_NODES);
    scan_kernel<<<1, 1024, 0, stream>>>(cnt, offsets, cursor, N_NODES);
    fill_csr <<<(N_EDGES + 255) / 256, 256, 0, stream>>>(e_src, e_dst, cursor, csr, N_EDGES);

    prep_w<<<384, 256, 0, stream>>>(W1, W2, Wmu, Wlv, w1t, w2t, bt3);
    conv_x<<<(N_NODES * 32 + 255) / 256, 256, 0, stream>>>((const float4*)x, (ushort4*)S0, dinv, N_NODES * 32);

    // q1 = prop(x*dinv)                       S0 -> S1
    prop_b<<<12500, 256, 0, stream>>>((const ushort2*)S0, (ushort2*)S1, csr, offsets, dinv, N_NODES);
    // h = prelu(q1@W1+b1); bf16 h*dinv        S1 -> S2
    gemm12<0><<<391, 256, 0, stream>>>(S1, w1t, b1, a1, dinv, nullptr, S2, N_NODES);
    // q2 = prop(h*dinv)                       S2 -> S3
    prop_b<<<12500, 256, 0, stream>>>((const ushort2*)S2, (ushort2*)S3, csr, offsets, dinv, N_NODES);
    // hgcn = prelu(q2@W2+b2) fp32 -> out; bf16 hgcn*dinv -> S0
    gemm12<1><<<391, 256, 0, stream>>>(S3, w2t, b2, a2, dinv, out_hgcn, S0, N_NODES);
    // p = prop(hgcn*dinv)                     S0 -> P
    prop_b<<<12500, 256, 0, stream>>>((const ushort2*)S0, (ushort2*)P, csr, offsets, dinv, N_NODES);

    dim3 g3(4, 391);
    if (fused) {
        gemm3<1><<<g3, 256, 0, stream>>>(P, bt3, bmu, blv, amu, alv, Wr, br, eps,
                                         out_mu, out_lv, out_hk, out_r, N_NODES);
    } else {
        gemm3<0><<<g3, 256, 0, stream>>>(P, bt3, bmu, blv, amu, alv, Wr, br, eps,
                                         out_mu, out_lv, out_hk, out_r, N_NODES);
        hk_kernel<<<12500, 256, 0, stream>>>(out_mu, out_lv, eps, Wr, br, out_hk, out_r, N_NODES);
    }
}

// Round 3
// 291.684 us; speedup vs baseline: 2.1649x; 1.2257x over previous
//
#include <hip/hip_runtime.h>
#include <math.h>

#define N_NODES 50000
#define N_EDGES 800000
#define HDIM 128
#define KD 256   // K*D

typedef float f32x4 __attribute__((ext_vector_type(4)));
typedef short s16x8 __attribute__((ext_vector_type(8)));

__device__ __forceinline__ ushort f2b(float f) {
    union { float f; unsigned u; } x; x.f = f;
    unsigned u = x.u;
    return (ushort)((u + 0x7FFF + ((u >> 16) & 1)) >> 16);   // RNE
}
__device__ __forceinline__ float b2f(ushort h) {
    union { unsigned u; float f; } x; x.u = ((unsigned)h) << 16; return x.f;
}

// ------------------------------------------------------------------ CSR build
__global__ void zero_int(int* __restrict__ p, int n) {
    int i = blockIdx.x * blockDim.x + threadIdx.x;
    if (i < n) p[i] = 0;
}

__global__ void count_deg(const int* __restrict__ dst, int* __restrict__ cnt, int e) {
    int i = blockIdx.x * blockDim.x + threadIdx.x;
    if (i < e) atomicAdd(&cnt[dst[i]], 1);
}

__global__ void calc_dinv(const int* __restrict__ cnt, float* __restrict__ dinv, int n) {
    int i = blockIdx.x * blockDim.x + threadIdx.x;
    if (i < n) dinv[i] = rsqrtf((float)(cnt[i] + 1));
}

// hierarchical scan: block-local exclusive scans + per-block totals
__global__ __launch_bounds__(1024)
void scan_blk(const int* __restrict__ cnt, int* __restrict__ offsets,
              int* __restrict__ blocksum, int n) {
    __shared__ int wsum[16];
    int tid = threadIdx.x;
    int i = blockIdx.x * 1024 + tid;
    int lane = tid & 63, wid = tid >> 6;
    int v = (i < n) ? cnt[i] : 0;
    int x = v;
    #pragma unroll
    for (int off = 1; off < 64; off <<= 1) {
        int t = __shfl_up(x, off, 64);
        if (lane >= off) x += t;
    }
    if (lane == 63) wsum[wid] = x;
    __syncthreads();
    if (wid == 0) {
        int w = (lane < 16) ? wsum[lane] : 0;
        #pragma unroll
        for (int off = 1; off < 16; off <<= 1) {
            int t = __shfl_up(w, off, 64);
            if (lane >= off) w += t;
        }
        if (lane < 16) wsum[lane] = w;
    }
    __syncthreads();
    int waveoff = (wid > 0) ? wsum[wid - 1] : 0;
    if (i < n) offsets[i] = x + waveoff - v;               // block-local exclusive
    if (tid == 1023) blocksum[blockIdx.x] = x + waveoff;   // block total
}

__global__ void scan_top(const int* __restrict__ blocksum, int* __restrict__ blockpref,
                         int* __restrict__ offsets, int nb, int n) {
    int lane = threadIdx.x;   // launched with 64 threads, nb <= 64
    int v = (lane < nb) ? blocksum[lane] : 0;
    int x = v;
    #pragma unroll
    for (int off = 1; off < 64; off <<= 1) {
        int t = __shfl_up(x, off, 64);
        if (lane >= off) x += t;
    }
    if (lane < nb) blockpref[lane] = x - v;
    if (lane == 63) offsets[n] = x;   // grand total
}

__global__ __launch_bounds__(1024)
void scan_add(int* __restrict__ offsets, int* __restrict__ cursor,
              const int* __restrict__ blockpref, int n) {
    int i = blockIdx.x * 1024 + threadIdx.x;
    if (i < n) {
        int o = offsets[i] + blockpref[blockIdx.x];
        offsets[i] = o;
        cursor[i] = o;
    }
}

__global__ void fill_csr(const int* __restrict__ src, const int* __restrict__ dst,
                         int* __restrict__ cursor, int* __restrict__ csr, int e) {
    int i = blockIdx.x * blockDim.x + threadIdx.x;
    if (i < e) {
        int d = dst[i];
        int pos = atomicAdd(&cursor[d], 1);
        csr[pos] = src[i];
    }
}

// ------------------------------------------------------------------ prep
// x (fp32) -> bf16, pre-scaled by dinv[row]
__global__ void conv_x(const float4* __restrict__ x, ushort4* __restrict__ o,
                       const float* __restrict__ dinv, int n4) {
    int i = blockIdx.x * 256 + threadIdx.x;
    if (i >= n4) return;
    int row = i >> 5;                 // 32 float4 per row
    float dv = dinv[row];
    float4 v = x[i];
    ushort4 u;
    u.x = f2b(v.x * dv); u.y = f2b(v.y * dv);
    u.z = f2b(v.z * dv); u.w = f2b(v.w * dv);
    o[i] = u;
}

// transpose + bf16 all weights: W1T[n][k], W2T[n][k], Bt3[k][n(mu|lv)][h]
__global__ void prep_w(const float* __restrict__ W1, const float* __restrict__ W2,
                       const float* __restrict__ Wmu, const float* __restrict__ Wlv,
                       ushort* __restrict__ w1t, ushort* __restrict__ w2t,
                       ushort* __restrict__ bt3) {
    int i = blockIdx.x * 256 + threadIdx.x;
    if (i < 16384) {
        int nn = i >> 7, k = i & 127;
        w1t[i] = f2b(W1[k * 128 + nn]);
    } else if (i < 32768) {
        int j = i - 16384; int nn = j >> 7, k = j & 127;
        w2t[j] = f2b(W2[k * 128 + nn]);
    } else if (i < 98304) {
        int j = i - 32768;                 // ((k*128 + n)*128 + h)
        int h = j & 127; int nk = j >> 7; int nn = nk & 127; int k = nk >> 7;
        float v = (nn < 64) ? Wmu[k * 8192 + h * 64 + nn]
                            : Wlv[k * 8192 + h * 64 + (nn - 64)];
        bt3[j] = f2b(v);
    }
}

// ------------------------------------------------------------------ propagate (bf16)
// input rows PRE-SCALED by dinv[src]; out[i] = dinv[i] * (sum_nbr in[s] + in[i])
// wave = 1 node; 4x16-lane groups, group g takes edges j == g (mod 4);
// each group covers the full 256B row with dwordx4 loads (16B/lane).
__global__ __launch_bounds__(256)
void prop_b(const ushort* __restrict__ hin, ushort* __restrict__ hout,
            const int* __restrict__ csr, const int* __restrict__ offsets,
            const float* __restrict__ dinv, int n) {
    int gw = blockIdx.x * 4 + (threadIdx.x >> 6);
    if (gw >= n) return;
    int lane = threadIdx.x & 63;
    int grp = lane >> 4, gl = lane & 15;
    int coff = gl << 3;               // element offset within row
    int beg = offsets[gw], end = offsets[gw + 1];
    float a0[8] = {0.f,0.f,0.f,0.f,0.f,0.f,0.f,0.f};
    float a1[8] = {0.f,0.f,0.f,0.f,0.f,0.f,0.f,0.f};
    for (int base = beg; base < end; base += 64) {
        int cnt = end - base; if (cnt > 64) cnt = 64;
        int sidx = (lane < cnt) ? csr[base + lane] : 0;
        int j = grp;
        for (; j + 4 < cnt; j += 8) {
            int s0 = __shfl(sidx, j, 64);
            int s1 = __shfl(sidx, j + 4, 64);
            s16x8 v0 = *(const s16x8*)(hin + (s0 << 7) + coff);
            s16x8 v1 = *(const s16x8*)(hin + (s1 << 7) + coff);
            #pragma unroll
            for (int q = 0; q < 8; ++q) {
                a0[q] += b2f((ushort)v0[q]);
                a1[q] += b2f((ushort)v1[q]);
            }
        }
        if (j < cnt) {
            int s0 = __shfl(sidx, j, 64);
            s16x8 v0 = *(const s16x8*)(hin + (s0 << 7) + coff);
            #pragma unroll
            for (int q = 0; q < 8; ++q) a0[q] += b2f((ushort)v0[q]);
        }
    }
    #pragma unroll
    for (int q = 0; q < 8; ++q) {
        float t = a0[q] + a1[q];
        t += __shfl_xor(t, 16, 64);
        t += __shfl_xor(t, 32, 64);
        a0[q] = t;
    }
    if (grp == 0) {
        s16x8 sv = *(const s16x8*)(hin + (gw << 7) + coff);
        float dn = dinv[gw];
        s16x8 o;
        #pragma unroll
        for (int q = 0; q < 8; ++q) {
            float t = (a0[q] + b2f((ushort)sv[q])) * dn;
            o[q] = (short)f2b(t);
        }
        *(s16x8*)(hout + (gw << 7) + coff) = o;
    }
}

// ------------------------------------------------------------------ MFMA GEMM (M x 128 @ 128 x 128)
// C = prelu(A@B + bias, alpha); Cb (bf16) = C * dinv[row] (feeds next prop)
// MODE 1 additionally writes fp32 C to Cf (hgcn output)
template<int MODE>
__global__ __launch_bounds__(256)
void gemm12(const ushort* __restrict__ A, const ushort* __restrict__ Bt,
            const float* __restrict__ bias, const float* __restrict__ alpha,
            const float* __restrict__ dinv,
            float* __restrict__ Cf, ushort* __restrict__ Cb, int nrows) {
    __shared__ char As[32768];
    __shared__ char Bs[32768];
    int tid = threadIdx.x;
    int row0 = blockIdx.x * 128;
    #pragma unroll
    for (int it = 0; it < 8; ++it) {
        int idx = tid + it * 256;
        int r = idx >> 4, cb = (idx & 15) << 4;
        int sw = cb ^ ((r & 15) << 4);
        uint4 v = make_uint4(0, 0, 0, 0);
        int row = row0 + r;
        if (row < nrows) v = *(const uint4*)((const char*)A + (size_t)row * 256 + cb);
        *(uint4*)(As + r * 256 + sw) = v;
        uint4 bv = *(const uint4*)((const char*)Bt + (size_t)idx * 16);
        *(uint4*)(Bs + r * 256 + sw) = bv;
    }
    __syncthreads();

    int w = tid >> 6, lane = tid & 63;
    int bq = lane >> 4, tr = lane & 15;
    f32x4 acc[2][8];
    #pragma unroll
    for (int mi = 0; mi < 2; ++mi)
        #pragma unroll
        for (int nj = 0; nj < 8; ++nj)
            acc[mi][nj] = (f32x4){0.f, 0.f, 0.f, 0.f};

    #pragma unroll
    for (int s = 0; s < 4; ++s) {
        int xoff = (s * 64 + bq * 16) ^ ((tr & 15) << 4);
        s16x8 af[2], bfr[8];
        #pragma unroll
        for (int mi = 0; mi < 2; ++mi)
            af[mi] = *(const s16x8*)(As + (w * 32 + mi * 16 + tr) * 256 + xoff);
        #pragma unroll
        for (int nj = 0; nj < 8; ++nj)
            bfr[nj] = *(const s16x8*)(Bs + (nj * 16 + tr) * 256 + xoff);
        #pragma unroll
        for (int mi = 0; mi < 2; ++mi)
            #pragma unroll
            for (int nj = 0; nj < 8; ++nj)
                acc[mi][nj] = __builtin_amdgcn_mfma_f32_16x16x32_bf16(af[mi], bfr[nj], acc[mi][nj], 0, 0, 0);
    }

    int g = lane >> 4, c = lane & 15;
    float aval = alpha[0];
    float bb[8];
    #pragma unroll
    for (int nj = 0; nj < 8; ++nj) bb[nj] = bias[nj * 16 + c];
    #pragma unroll
    for (int mi = 0; mi < 2; ++mi) {
        #pragma unroll
        for (int j = 0; j < 4; ++j) {
            int row = row0 + w * 32 + mi * 16 + g * 4 + j;
            if (row >= nrows) continue;
            float dv = dinv[row];
            #pragma unroll
            for (int nj = 0; nj < 8; ++nj) {
                int col = nj * 16 + c;
                float t = acc[mi][nj][j] + bb[nj];
                t = t >= 0.f ? t : aval * t;
                if (MODE) Cf[(size_t)row * 128 + col] = t;
                Cb[(size_t)row * 128 + col] = f2b(t * dv);
            }
        }
    }
}

// ------------------------------------------------------------------ mu/lv GEMM (+ fused hk, r)
// blockIdx.x = k; B tile = Bt3[k] : cols 0-63 mu, 64-127 lv
template<int FUSED>
__global__ __launch_bounds__(256)
void gemm3(const ushort* __restrict__ A, const ushort* __restrict__ Bt3,
           const float* __restrict__ bmu, const float* __restrict__ blv,
           const float* __restrict__ amu, const float* __restrict__ alv,
           const float* __restrict__ Wr, const float* __restrict__ br,
           const float* __restrict__ eps,
           float* __restrict__ out_mu, float* __restrict__ out_lv,
           float* __restrict__ out_hk, float* __restrict__ out_r, int nrows) {
    __shared__ char As[32768];
    __shared__ char Bs[32768];
    int tid = threadIdx.x;
    int k = blockIdx.x;
    int row0 = blockIdx.y * 128;
    const ushort* Bt = Bt3 + (size_t)k * 16384;
    #pragma unroll
    for (int it = 0; it < 8; ++it) {
        int idx = tid + it * 256;
        int r = idx >> 4, cb = (idx & 15) << 4;
        int sw = cb ^ ((r & 15) << 4);
        uint4 v = make_uint4(0, 0, 0, 0);
        int row = row0 + r;
        if (row < nrows) v = *(const uint4*)((const char*)A + (size_t)row * 256 + cb);
        *(uint4*)(As + r * 256 + sw) = v;
        uint4 bv = *(const uint4*)((const char*)Bt + (size_t)idx * 16);
        *(uint4*)(Bs + r * 256 + sw) = bv;
    }
    __syncthreads();

    int w = tid >> 6, lane = tid & 63;
    int bq = lane >> 4, tr = lane & 15;
    f32x4 acc[2][8];
    #pragma unroll
    for (int mi = 0; mi < 2; ++mi)
        #pragma unroll
        for (int nj = 0; nj < 8; ++nj)
            acc[mi][nj] = (f32x4){0.f, 0.f, 0.f, 0.f};

    #pragma unroll
    for (int s = 0; s < 4; ++s) {
        int xoff = (s * 64 + bq * 16) ^ ((tr & 15) << 4);
        s16x8 af[2], bfr[8];
        #pragma unroll
        for (int mi = 0; mi < 2; ++mi)
            af[mi] = *(const s16x8*)(As + (w * 32 + mi * 16 + tr) * 256 + xoff);
        #pragma unroll
        for (int nj = 0; nj < 8; ++nj)
            bfr[nj] = *(const s16x8*)(Bs + (nj * 16 + tr) * 256 + xoff);
        #pragma unroll
        for (int mi = 0; mi < 2; ++mi)
            #pragma unroll
            for (int nj = 0; nj < 8; ++nj)
                acc[mi][nj] = __builtin_amdgcn_mfma_f32_16x16x32_bf16(af[mi], bfr[nj], acc[mi][nj], 0, 0, 0);
    }

    int g = lane >> 4, c = lane & 15;
    float amuv = amu[k], alvv = alv[k];
    float brk = br[k];
    float bmv[4], blvb[4], wrv[4];
    #pragma unroll
    for (int nj = 0; nj < 4; ++nj) {
        int d = nj * 16 + c;
        bmv[nj] = bmu[k * 64 + d];
        blvb[nj] = blv[k * 64 + d];
        wrv[nj] = FUSED ? Wr[k * 64 + d] : 0.f;
    }
    #pragma unroll
    for (int mi = 0; mi < 2; ++mi) {
        float rsum[4] = {0.f, 0.f, 0.f, 0.f};
        #pragma unroll
        for (int j = 0; j < 4; ++j) {
            int row = row0 + w * 32 + mi * 16 + g * 4 + j;
            if (row >= nrows) continue;
            #pragma unroll
            for (int nj = 0; nj < 4; ++nj) {
                int d = nj * 16 + c;
                size_t oc = (size_t)row * KD + k * 64 + d;
                float m_ = acc[mi][nj][j] + bmv[nj];
                m_ = m_ >= 0.f ? m_ : amuv * m_;
                float l_ = acc[mi][nj + 4][j] + blvb[nj];
                l_ = l_ >= 0.f ? l_ : alvv * l_;
                l_ = 1.f / (1.f + __expf(-l_));
                out_mu[oc] = m_;
                out_lv[oc] = l_;
                if (FUSED) {
                    float h = fmaf(eps[oc], __expf(0.5f * l_), m_);
                    out_hk[oc] = h;
                    rsum[j] = fmaf(h, wrv[nj], rsum[j]);
                }
            }
        }
        if (FUSED) {
            #pragma unroll
            for (int j = 0; j < 4; ++j) {
                float t = rsum[j];
                t += __shfl_xor(t, 1, 64);
                t += __shfl_xor(t, 2, 64);
                t += __shfl_xor(t, 4, 64);
                t += __shfl_xor(t, 8, 64);
                if (c == 0) {
                    int row = row0 + w * 32 + mi * 16 + g * 4 + j;
                    if (row < nrows)
                        out_r[(size_t)row * 4 + k] = 1.f / (1.f + __expf(-(t + brk)));
                }
            }
        }
    }
}

// ------------------------------------------------------------------ fallback reparam + r
__global__ void hk_kernel(const float* __restrict__ mu, const float* __restrict__ lv,
                          const float* __restrict__ eps, const float* __restrict__ Wr,
                          const float* __restrict__ br, float* __restrict__ hk,
                          float* __restrict__ r, int n) {
    int gw = (blockIdx.x * blockDim.x + threadIdx.x) >> 6;
    int lane = threadIdx.x & 63;
    if (gw >= n) return;
    size_t base = (size_t)gw * KD;
    #pragma unroll
    for (int k = 0; k < 4; ++k) {
        int c = k * 64 + lane;
        float m = mu[base + c], v = lv[base + c], e = eps[base + c];
        float h = fmaf(e, __expf(0.5f * v), m);
        hk[base + c] = h;
        float t = h * Wr[k * 64 + lane];
        #pragma unroll
        for (int off = 32; off >= 1; off >>= 1) t += __shfl_xor(t, off, 64);
        if (lane == 0) r[(size_t)gw * 4 + k] = 1.f / (1.f + __expf(-(t + br[k])));
    }
}

// ------------------------------------------------------------------ launch
extern "C" void kernel_launch(void* const* d_in, const int* in_sizes, int n_in,
                              void* d_out, int out_size, void* d_ws, size_t ws_size,
                              hipStream_t stream) {
    const float* x   = (const float*)d_in[0];
    const int*   ei  = (const int*)d_in[1];
    const float* W1  = (const float*)d_in[2];
    const float* b1  = (const float*)d_in[3];
    const float* a1  = (const float*)d_in[4];
    const float* W2  = (const float*)d_in[5];
    const float* b2  = (const float*)d_in[6];
    const float* a2  = (const float*)d_in[7];
    const float* Wmu = (const float*)d_in[8];
    const float* bmu = (const float*)d_in[9];
    const float* amu = (const float*)d_in[10];
    const float* Wlv = (const float*)d_in[11];
    const float* blv = (const float*)d_in[12];
    const float* alv = (const float*)d_in[13];
    const float* Wr  = (const float*)d_in[14];
    const float* br  = (const float*)d_in[15];
    const float* eps = (const float*)d_in[16];

    float* out      = (float*)d_out;
    float* out_hgcn = out;                                  // N*128
    float* out_lv   = out + (size_t)N_NODES * HDIM;         // N*256
    float* out_mu   = out_lv + (size_t)N_NODES * KD;        // N*256
    float* out_hk   = out_mu + (size_t)N_NODES * KD;        // N*256
    float* out_r    = out_hk + (size_t)N_NODES * KD;        // N*4

    char* ws = (char*)d_ws;
    int*    cnt      = (int*)ws;                       // N ints
    int*    offsets  = (int*)(ws + 204800);            // N+1 ints
    int*    cursor   = (int*)(ws + 409600);            // N ints
    int*    csr      = (int*)(ws + 614400);            // E ints
    float*  dinv     = (float*)(ws + 3814400);         // N floats
    ushort* w1t      = (ushort*)(ws + 4014592);        // 16384 bf16
    ushort* w2t      = (ushort*)(ws + 4047360);        // 16384 bf16
    ushort* bt3      = (ushort*)(ws + 4080128);        // 65536 bf16 (ends 4211200)
    int*    blocksum = (int*)(ws + 4211200);           // 49 ints
    int*    blockpref= (int*)(ws + 4211456);           // 49 ints

    // bf16 N x 128 slots inside the hk output region (fully rewritten at the end)
    ushort* S0 = (ushort*)out_hk;
    ushort* S1 = S0 + (size_t)N_NODES * HDIM;
    ushort* S2 = S1 + (size_t)N_NODES * HDIM;
    ushort* S3 = S2 + (size_t)N_NODES * HDIM;

    const size_t P_OFF = 4211712;
    const bool fused = ws_size >= P_OFF + (size_t)N_NODES * HDIM * 2;
    ushort* P = fused ? (ushort*)(ws + P_OFF) : S1;

    const int* e_src = ei;
    const int* e_dst = ei + N_EDGES;
    const int NB = (N_NODES + 1023) / 1024;   // 49

    zero_int <<<(N_NODES + 255) / 256, 256, 0, stream>>>(cnt, N_NODES);
    count_deg<<<(N_EDGES + 255) / 256, 256, 0, stream>>>(e_dst, cnt, N_EDGES);
    calc_dinv<<<(N_NODES + 255) / 256, 256, 0, stream>>>(cnt, dinv, N_NODES);
    scan_blk <<<NB, 1024, 0, stream>>>(cnt, offsets, blocksum, N_NODES);
    scan_top <<<1, 64, 0, stream>>>(blocksum, blockpref, offsets, NB, N_NODES);
    scan_add <<<NB, 1024, 0, stream>>>(offsets, cursor, blockpref, N_NODES);
    fill_csr <<<(N_EDGES + 255) / 256, 256, 0, stream>>>(e_src, e_dst, cursor, csr, N_EDGES);

    prep_w<<<384, 256, 0, stream>>>(W1, W2, Wmu, Wlv, w1t, w2t, bt3);
    conv_x<<<(N_NODES * 32 + 255) / 256, 256, 0, stream>>>((const float4*)x, (ushort4*)S0, dinv, N_NODES * 32);

    // q1 = prop(x*dinv)                       S0 -> S1
    prop_b<<<12500, 256, 0, stream>>>(S0, S1, csr, offsets, dinv, N_NODES);
    // h = prelu(q1@W1+b1); bf16 h*dinv        S1 -> S2
    gemm12<0><<<391, 256, 0, stream>>>(S1, w1t, b1, a1, dinv, nullptr, S2, N_NODES);
    // q2 = prop(h*dinv)                       S2 -> S3
    prop_b<<<12500, 256, 0, stream>>>(S2, S3, csr, offsets, dinv, N_NODES);
    // hgcn = prelu(q2@W2+b2) fp32 -> out; bf16 hgcn*dinv -> S0
    gemm12<1><<<391, 256, 0, stream>>>(S3, w2t, b2, a2, dinv, out_hgcn, S0, N_NODES);
    // p = prop(hgcn*dinv)                     S0 -> P
    prop_b<<<12500, 256, 0, stream>>>(S0, P, csr, offsets, dinv, N_NODES);

    dim3 g3(4, 391);
    if (fused) {
        gemm3<1><<<g3, 256, 0, stream>>>(P, bt3, bmu, blv, amu, alv, Wr, br, eps,
                                         out_mu, out_lv, out_hk, out_r, N_NODES);
    } else {
        gemm3<0><<<g3, 256, 0, stream>>>(P, bt3, bmu, blv, amu, alv, Wr, br, eps,
                                         out_mu, out_lv, out_hk, out_r, N_NODES);
        hk_kernel<<<12500, 256, 0, stream>>>(out_mu, out_lv, eps, Wr, br, out_hk, out_r, N_NODES);
    }
}